// Round 6
// baseline (272.497 us; speedup 1.0000x reference)
//
#include <hip/hip_runtime.h>

// GatedCrossModalAttention: B=16384, NM=5, D=256. FP32 I/O, bf16 internal.
// Attention collapses (Lq=Lk=1): branch_s(x) = x[:,mod_s] @ (Wo_s@Wv_s)^T + (Wo_s@bv_s+bo_s).
// R3: shfl(ds_bpermute) saturates LDS pipe -> DPP+readlane (VALU).
// R4: update_dpp ctrl must be compile-time const -> template param.
// R5: bf16-MFMA gate logits -> absmax 0.109 > 0.1025. Gates MUST stay fp32.
// ws use: WF 640KB + BF 5KB (R3 proved this size usable).

typedef __attribute__((ext_vector_type(8))) short short8;
typedef __attribute__((ext_vector_type(4))) float floatx4;

__device__ __forceinline__ float b2f(unsigned short h){ return __uint_as_float((unsigned)h << 16); }
__device__ __forceinline__ unsigned short f2b(float f){
    unsigned u = __float_as_uint(f);
    return (unsigned short)((u + 0x7FFFu + ((u >> 16) & 1u)) >> 16);
}

template<int CTRL>
__device__ __forceinline__ float dpp_add(float v){
    int x = __builtin_amdgcn_update_dpp(0, __float_as_int(v), CTRL, 0xf, 0xf, true);
    return v + __int_as_float(x);
}
// sum across 64 lanes, result broadcast (VALU pipe only + 1 readlane)
__device__ __forceinline__ float wsum(float v){
    v = dpp_add<0x111>(v);  // row_shr:1
    v = dpp_add<0x112>(v);  // row_shr:2
    v = dpp_add<0x114>(v);  // row_shr:4
    v = dpp_add<0x118>(v);  // row_shr:8
    v = dpp_add<0x142>(v);  // row_bcast:15
    v = dpp_add<0x143>(v);  // row_bcast:31
    return __int_as_float(__builtin_amdgcn_readlane(__float_as_int(v), 63));
}

// ---------------- K1: weight fusion ----------------
// grid (64,5), block 256: 4 output rows of WF_s per block + bias via wave/row.
__global__ __launch_bounds__(256) void k_fuse(
    const float* __restrict__ sWi, const float* __restrict__ sbi,
    const float* __restrict__ sWo, const float* __restrict__ sbo,
    const float* __restrict__ cWi, const float* __restrict__ cbi,
    const float* __restrict__ cWo, const float* __restrict__ cbo,
    unsigned short* __restrict__ WF, float* __restrict__ BF)
{
    int s = blockIdx.y;
    int i0 = blockIdx.x * 4;
    int tid = threadIdx.x;
    int wave = tid >> 6, lane = tid & 63;
    const float *Wo, *Wv, *bv, *bo;
    if (s == 0) { Wo = sWo; Wv = sWi + 512 * 256; bv = sbi + 512; bo = sbo; }
    else {
        int n = s - 1;
        Wo = cWo + n * 65536;
        Wv = cWi + n * 768 * 256 + 512 * 256;
        bv = cbi + n * 768 + 512;
        bo = cbo + n * 256;
    }
    __shared__ float wo[4 * 256];
    #pragma unroll
    for (int it = 0; it < 4; ++it) {
        int idx = tid + it * 256;
        wo[idx] = Wo[i0 * 256 + idx];
    }
    __syncthreads();
    float a0 = 0.f, a1 = 0.f, a2 = 0.f, a3 = 0.f;
    #pragma unroll 8
    for (int k = 0; k < 256; ++k) {
        float wv = Wv[k * 256 + tid];
        a0 += wo[k] * wv;
        a1 += wo[256 + k] * wv;
        a2 += wo[512 + k] * wv;
        a3 += wo[768 + k] * wv;
    }
    unsigned short* dst = WF + ((size_t)s * 256 + i0) * 256 + tid;
    dst[0] = f2b(a0); dst[256] = f2b(a1); dst[512] = f2b(a2); dst[768] = f2b(a3);
    // bias: wave w -> row i0+w, DPP reduce
    {
        int i = i0 + wave;
        float4 a = *(const float4*)(Wo + (size_t)i * 256 + lane * 4);
        float4 b = *(const float4*)(bv + lane * 4);
        float p = a.x * b.x + a.y * b.y + a.z * b.z + a.w * b.w;
        p = wsum(p);
        if (lane == 0) BF[s * 256 + i] = p + bo[i];
    }
}

// ---------------- K2: fused GEMM + epilogue ----------------
// grid 1024, block 256 (4 waves), 16 rows/block.
// Ax: all 5 modal slices, bf16, MFMA-frag-swizzled: halfword index
//   AX(mod,kk,q4,slot,j) = (((mod*8+kk)*4+q4)*16 + slot)*8 + j, slot = row ^ ((kk*4+q4)&15)
// -> A-frag reads are 64 distinct 16B chunks in a 1KB region: conflict-free.
__global__ __launch_bounds__(256, 3) void k_main(
    const float* __restrict__ x, const unsigned short* __restrict__ WF,
    const float* __restrict__ BF,
    const float* __restrict__ cln_g, const float* __restrict__ cln_b,
    const float* __restrict__ gln_g, const float* __restrict__ gln_b,
    const float* __restrict__ gW, const float* __restrict__ gb,
    const float* __restrict__ fln_g, const float* __restrict__ fln_b,
    const int* __restrict__ midx, float* __restrict__ out)
{
    __shared__ __align__(16) unsigned short Ax[20480];     // 40960 B
    __shared__ __align__(16) unsigned short Yb[16 * 264];  // 8448 B

    int m = midx[0];
    int b0 = blockIdx.x * 16;
    int tid = threadIdx.x;
    int wave = tid >> 6, lane = tid & 63;
    int l16 = lane & 15, q4 = lane >> 4;

    // ---- stage x[b0:b0+16, :, :] -> Ax (swizzled bf16) ----
    #pragma unroll
    for (int it = 0; it < 20; ++it) {
        int idx = tid + it * 256;           // float4 index within block's 5120 chunks
        int row = idx / 320;                // 320 float4 per row
        int rem = idx - row * 320;
        int mod = rem >> 6;
        int c = (rem & 63) << 2;            // element col, multiple of 4
        float4 v = *(const float4*)(x + (size_t)b0 * 1280 + (size_t)idx * 4);
        int kk = c >> 5, qq = (c >> 3) & 3, j = c & 7;
        int slot = row ^ ((kk * 4 + qq) & 15);
        uint2 p;
        p.x = (unsigned)f2b(v.x) | ((unsigned)f2b(v.y) << 16);
        p.y = (unsigned)f2b(v.z) | ((unsigned)f2b(v.w) << 16);
        *(uint2*)(Ax + ((((mod * 8 + kk) * 4 + qq) * 16 + slot) * 8 + j)) = p;
    }

    // ---- q rows (fp32) for this wave's 4 epilogue rows ----
    float4 qv[4];
    #pragma unroll
    for (int rr = 0; rr < 4; ++rr)
        qv[rr] = *(const float4*)(x + ((size_t)(b0 + wave * 4 + rr) * 5 + m) * 256 + lane * 4);

    __syncthreads();  // Ax ready

    // ---- gates per row: fp32 LN(q) . gW (R5 lesson: bf16 here fails threshold) ----
    float4 glg = *(const float4*)(gln_g + lane * 4);
    float4 glb = *(const float4*)(gln_b + lane * 4);
    float4 gwv[5];
    float gbv[5];
    #pragma unroll
    for (int n = 0; n < 5; ++n) {
        gwv[n] = *(const float4*)(gW + n * 256 + lane * 4);
        gbv[n] = gb[n];
    }
    float gte[4][5];  // gates per row (wave-uniform values)
    #pragma unroll
    for (int rr = 0; rr < 4; ++rr) {
        float s1 = wsum(qv[rr].x + qv[rr].y + qv[rr].z + qv[rr].w);
        float s2 = wsum(qv[rr].x * qv[rr].x + qv[rr].y * qv[rr].y +
                        qv[rr].z * qv[rr].z + qv[rr].w * qv[rr].w);
        float mn = s1 * (1.f / 256.f);
        float vr = s2 * (1.f / 256.f) - mn * mn;
        float rs = rsqrtf(vr + 1e-5f);
        float q0 = (qv[rr].x - mn) * rs * glg.x + glb.x;
        float q1 = (qv[rr].y - mn) * rs * glg.y + glb.y;
        float q2 = (qv[rr].z - mn) * rs * glg.z + glb.z;
        float q3 = (qv[rr].w - mn) * rs * glg.w + glb.w;
        float lg[5];
        #pragma unroll
        for (int n = 0; n < 5; ++n) {
            float p = q0 * gwv[n].x + q1 * gwv[n].y + q2 * gwv[n].z + q3 * gwv[n].w;
            lg[n] = wsum(p) + gbv[n];
        }
        float mx = lg[0];
        #pragma unroll
        for (int n = 1; n < 5; ++n) mx = fmaxf(mx, lg[n]);
        float es = 0.f;
        #pragma unroll
        for (int n = 0; n < 5; ++n) { lg[n] = __expf(lg[n] - mx); es += lg[n]; }
        float inv = 1.f / es;
        #pragma unroll
        for (int n = 0; n < 5; ++n) gte[rr][n] = lg[n] * inv;
    }

    float comb[4][4];
    #pragma unroll
    for (int rr = 0; rr < 4; ++rr)
        #pragma unroll
        for (int i = 0; i < 4; ++i) comb[rr][i] = 0.f;

    // ---- branch loop ----
    for (int s = 0; s < 5; ++s) {
        int mod = (s == 0) ? m : ((s - 1 < m) ? s - 1 : s);
        floatx4 acc[4];
        #pragma unroll
        for (int ct = 0; ct < 4; ++ct) acc[ct] = (floatx4){0.f, 0.f, 0.f, 0.f};
        const unsigned short* wB = WF + (size_t)s * 65536;
        #pragma unroll
        for (int kk = 0; kk < 8; ++kk) {
            int slot = l16 ^ ((kk * 4 + q4) & 15);
            short8 a = *(const short8*)(Ax + (((mod * 8 + kk) * 4 + q4) * 16 + slot) * 8);
            short8 bb[4];
            #pragma unroll
            for (int ct = 0; ct < 4; ++ct)
                bb[ct] = *(const short8*)(wB + (size_t)(wave * 64 + ct * 16 + l16) * 256 + kk * 32 + q4 * 8);
            #pragma unroll
            for (int ct = 0; ct < 4; ++ct)
                acc[ct] = __builtin_amdgcn_mfma_f32_16x16x32_bf16(a, bb[ct], acc[ct], 0, 0, 0);
        }
        // park in Yb (C-layout -> row-major bf16)
        #pragma unroll
        for (int ct = 0; ct < 4; ++ct)
            #pragma unroll
            for (int i = 0; i < 4; ++i)
                Yb[(q4 * 4 + i) * 264 + wave * 64 + ct * 16 + l16] = f2b(acc[ct][i]);
        __syncthreads();  // Yb ready

        float4 bfv = *(const float4*)(BF + s * 256 + lane * 4);
        if (s == 0) {
            #pragma unroll
            for (int rr = 0; rr < 4; ++rr) {
                int row = wave * 4 + rr;
                uint2 u = *(const uint2*)(Yb + row * 264 + lane * 4);
                float g0 = gte[rr][0];
                comb[rr][0] += g0 * (b2f(u.x & 0xffff) + bfv.x);
                comb[rr][1] += g0 * (b2f(u.x >> 16) + bfv.y);
                comb[rr][2] += g0 * (b2f(u.y & 0xffff) + bfv.z);
                comb[rr][3] += g0 * (b2f(u.y >> 16) + bfv.w);
            }
        } else {
            float4 cg = *(const float4*)(cln_g + (s - 1) * 256 + lane * 4);
            float4 cb = *(const float4*)(cln_b + (s - 1) * 256 + lane * 4);
            #pragma unroll
            for (int rr = 0; rr < 4; ++rr) {
                int row = wave * 4 + rr;
                uint2 u = *(const uint2*)(Yb + row * 264 + lane * 4);
                float t0 = qv[rr].x + b2f(u.x & 0xffff) + bfv.x;
                float t1 = qv[rr].y + b2f(u.x >> 16) + bfv.y;
                float t2 = qv[rr].z + b2f(u.y & 0xffff) + bfv.z;
                float t3 = qv[rr].w + b2f(u.y >> 16) + bfv.w;
                float s1 = wsum(t0 + t1 + t2 + t3);
                float s2 = wsum(t0 * t0 + t1 * t1 + t2 * t2 + t3 * t3);
                float mn = s1 * (1.f / 256.f);
                float vr = s2 * (1.f / 256.f) - mn * mn;
                float rs = rsqrtf(vr + 1e-5f);
                float gs = gte[rr][s];
                comb[rr][0] += gs * ((t0 - mn) * rs * cg.x + cb.x);
                comb[rr][1] += gs * ((t1 - mn) * rs * cg.y + cb.y);
                comb[rr][2] += gs * ((t2 - mn) * rs * cg.z + cb.z);
                comb[rr][3] += gs * ((t3 - mn) * rs * cg.w + cb.w);
            }
        }
        __syncthreads();  // Yb consumed; next branch may overwrite
    }

    // ---- final LN + store ----
    float4 fg = *(const float4*)(fln_g + lane * 4);
    float4 fb = *(const float4*)(fln_b + lane * 4);
    #pragma unroll
    for (int rr = 0; rr < 4; ++rr) {
        int row = wave * 4 + rr;
        float t0 = qv[rr].x + comb[rr][0];
        float t1 = qv[rr].y + comb[rr][1];
        float t2 = qv[rr].z + comb[rr][2];
        float t3 = qv[rr].w + comb[rr][3];
        float s1 = wsum(t0 + t1 + t2 + t3);
        float s2 = wsum(t0 * t0 + t1 * t1 + t2 * t2 + t3 * t3);
        float mn = s1 * (1.f / 256.f);
        float vr = s2 * (1.f / 256.f) - mn * mn;
        float rs = rsqrtf(vr + 1e-5f);
        float4 ov;
        ov.x = (t0 - mn) * rs * fg.x + fb.x;
        ov.y = (t1 - mn) * rs * fg.y + fb.y;
        ov.z = (t2 - mn) * rs * fg.z + fb.z;
        ov.w = (t3 - mn) * rs * fg.w + fb.w;
        *(float4*)(out + (size_t)(b0 + row) * 256 + lane * 4) = ov;
    }
}

extern "C" void kernel_launch(void* const* d_in, const int* in_sizes, int n_in,
                              void* d_out, int out_size, void* d_ws, size_t ws_size,
                              hipStream_t stream) {
    const float* x    = (const float*)d_in[0];
    const float* sWi  = (const float*)d_in[1];
    const float* sbi  = (const float*)d_in[2];
    const float* sWo  = (const float*)d_in[3];
    const float* sbo  = (const float*)d_in[4];
    const float* cWi  = (const float*)d_in[5];
    const float* cbi  = (const float*)d_in[6];
    const float* cWo  = (const float*)d_in[7];
    const float* cbo  = (const float*)d_in[8];
    const float* clng = (const float*)d_in[9];
    const float* clnb = (const float*)d_in[10];
    const float* glng = (const float*)d_in[11];
    const float* glnb = (const float*)d_in[12];
    const float* gW   = (const float*)d_in[13];
    const float* gb   = (const float*)d_in[14];
    const float* flng = (const float*)d_in[15];
    const float* flnb = (const float*)d_in[16];
    const int* midx   = (const int*)d_in[17];
    float* out        = (float*)d_out;

    char* ws = (char*)d_ws;
    unsigned short* WF = (unsigned short*)ws;           // 655360 B
    float* BF          = (float*)(ws + 655360);         // 5120 B

    k_fuse<<<dim3(64, 5), 256, 0, stream>>>(sWi, sbi, sWo, sbo, cWi, cbi, cWo, cbo, WF, BF);
    k_main<<<1024, 256, 0, stream>>>(x, WF, BF, clng, clnb, glng, glnb, gW, gb, flng, flnb, midx, out);
}